// Round 1
// baseline (783.768 us; speedup 1.0000x reference)
//
#include <hip/hip_runtime.h>

// SelfAttention (SAGAN-style), MI355X fp32 implementation.
// Math: out[b,c,n] = gamma * sum_m exp(S[m,n]) * V[b,c,m] / Z[m] + x[b,c,n]
//   where S[m,n] = sum_q Q[q,m]*K[q,n], Z[m] = sum_j exp(S[m,j]).
// (Reference contracts V with attention's *query* index; softmax axis is the
//  free index, so normalization folds into U = V/Z and partials just add.)

constexpr int Bn = 4;     // batch
constexpr int Cc = 64;    // channels
constexpr int Q8 = 8;     // C/8 qk channels
constexpr int Np = 4096;  // hw
constexpr int TM = 16;    // m-tile
constexpr int SLZ = 8;    // slices for Z pass

// ---------------- kernel 1: QKV projections (1x1 convs) ----------------
__global__ __launch_bounds__(256) void qkv_kernel(
    const float* __restrict__ x,
    const float* __restrict__ Wq, const float* __restrict__ bq,
    const float* __restrict__ Wk, const float* __restrict__ bk,
    const float* __restrict__ Wv, const float* __restrict__ bv,
    float* __restrict__ Qf, float* __restrict__ Kf, float* __restrict__ Vf)
{
    __shared__ float sWqT[Cc * Q8];  // [c][o]
    __shared__ float sWkT[Cc * Q8];
    __shared__ float sWvT[Cc * Cc];
    int t = threadIdx.x;
    for (int idx = t; idx < Q8 * Cc; idx += 256) {
        int o = idx >> 6, c = idx & 63;
        sWqT[c * Q8 + o] = Wq[idx];
        sWkT[c * Q8 + o] = Wk[idx];
    }
    for (int idx = t; idx < Cc * Cc; idx += 256) {
        int o = idx >> 6, c = idx & 63;
        sWvT[c * Cc + o] = Wv[idx];
    }
    __syncthreads();

    int gid = blockIdx.x * 256 + t;      // over Bn*Np
    int b = gid >> 12, n = gid & (Np - 1);

    float q[Q8], k[Q8], v[Cc];
    #pragma unroll
    for (int i = 0; i < Q8; i++) { q[i] = bq[i]; k[i] = bk[i]; }
    #pragma unroll
    for (int i = 0; i < Cc; i++) v[i] = bv[i];

    const float* xp = x + (size_t)(b * Cc) * Np + n;
    for (int c = 0; c < Cc; c++) {
        float xv = xp[(size_t)c * Np];
        const float4* wq4 = (const float4*)&sWqT[c * Q8];
        float4 w0 = wq4[0], w1 = wq4[1];
        q[0] += w0.x * xv; q[1] += w0.y * xv; q[2] += w0.z * xv; q[3] += w0.w * xv;
        q[4] += w1.x * xv; q[5] += w1.y * xv; q[6] += w1.z * xv; q[7] += w1.w * xv;
        const float4* wk4 = (const float4*)&sWkT[c * Q8];
        w0 = wk4[0]; w1 = wk4[1];
        k[0] += w0.x * xv; k[1] += w0.y * xv; k[2] += w0.z * xv; k[3] += w0.w * xv;
        k[4] += w1.x * xv; k[5] += w1.y * xv; k[6] += w1.z * xv; k[7] += w1.w * xv;
        const float4* wv4 = (const float4*)&sWvT[c * Cc];
        #pragma unroll
        for (int i4 = 0; i4 < Cc / 4; i4++) {
            float4 w = wv4[i4];
            v[i4 * 4 + 0] += w.x * xv;
            v[i4 * 4 + 1] += w.y * xv;
            v[i4 * 4 + 2] += w.z * xv;
            v[i4 * 4 + 3] += w.w * xv;
        }
    }
    #pragma unroll
    for (int i = 0; i < Q8; i++) {
        Qf[(size_t)(b * Q8 + i) * Np + n] = q[i];
        Kf[(size_t)(b * Q8 + i) * Np + n] = k[i];
    }
    #pragma unroll
    for (int i = 0; i < Cc; i++) Vf[(size_t)(b * Cc + i) * Np + n] = v[i];
}

// ---------------- kernel 2: Z[m] = sum_j exp(Q_m . K_j), sliced over j ----------------
__global__ __launch_bounds__(256) void zsum_kernel(
    const float* __restrict__ Qf, const float* __restrict__ Kf,
    float* __restrict__ ZP, int jms)
{
    int b = blockIdx.z, slice = blockIdx.y;
    int t = threadIdx.x;
    int m = blockIdx.x * 256 + t;
    __shared__ float Kt[Q8][TM];

    float qm[Q8];
    #pragma unroll
    for (int i = 0; i < Q8; i++) qm[i] = Qf[(size_t)(b * Q8 + i) * Np + m];

    float z = 0.f;
    int j0base = slice * jms;
    for (int jt = 0; jt < jms; jt += TM) {
        int j0 = j0base + jt;
        __syncthreads();
        if (t < 32) {
            int qi = t >> 2, j4 = t & 3;
            *(float4*)&Kt[qi][j4 * 4] =
                *(const float4*)&Kf[(size_t)(b * Q8 + qi) * Np + j0 + j4 * 4];
        }
        __syncthreads();
        float s[TM];
        #pragma unroll
        for (int j = 0; j < TM; j++) s[j] = 0.f;
        #pragma unroll
        for (int i = 0; i < Q8; i++) {
            const float4* k4 = (const float4*)&Kt[i][0];
            float qi = qm[i];
            #pragma unroll
            for (int j4 = 0; j4 < TM / 4; j4++) {
                float4 kv = k4[j4];
                s[j4 * 4 + 0] += qi * kv.x;
                s[j4 * 4 + 1] += qi * kv.y;
                s[j4 * 4 + 2] += qi * kv.z;
                s[j4 * 4 + 3] += qi * kv.w;
            }
        }
        #pragma unroll
        for (int j = 0; j < TM; j++) z += __expf(s[j]);
    }
    ZP[(size_t)(b * SLZ + slice) * Np + m] = z;
}

// ---------------- kernel 3: U = V / Z (in place on Vf) ----------------
__global__ __launch_bounds__(256) void u_kernel(
    const float* __restrict__ ZP, float* __restrict__ Vf)
{
    int gid = blockIdx.x * 256 + threadIdx.x;  // over Bn*Np
    int b = gid >> 12, m = gid & (Np - 1);
    float z = 0.f;
    #pragma unroll
    for (int sl = 0; sl < SLZ; ++sl) z += ZP[(size_t)(b * SLZ + sl) * Np + m];
    float zi = 1.f / z;
    float* vp = Vf + (size_t)(b * Cc) * Np + m;
    #pragma unroll
    for (int c = 0; c < Cc; c++) vp[(size_t)c * Np] *= zi;
}

// ---------------- kernel 4: out_partial[c,n] = sum_{m in slice} exp(Q_m.K_n) U[c,m] ----------------
__global__ __launch_bounds__(256) void attn_kernel(
    const float* __restrict__ Kf, const float* __restrict__ Qf,
    const float* __restrict__ Uf, float* __restrict__ PO, int ms)
{
    int b = blockIdx.z, slice = blockIdx.y;
    int t = threadIdx.x;
    int n = blockIdx.x * 256 + t;
    __shared__ float Qt[Q8][TM];
    __shared__ float Ut[Cc][TM];

    float kn[Q8];
    #pragma unroll
    for (int i = 0; i < Q8; i++) kn[i] = Kf[(size_t)(b * Q8 + i) * Np + n];

    float acc[Cc];
    #pragma unroll
    for (int c = 0; c < Cc; c++) acc[c] = 0.f;

    int m0base = slice * ms;
    for (int mt = 0; mt < ms; mt += TM) {
        int m0 = m0base + mt;
        __syncthreads();
        if (t < 32) {
            int qi = t >> 2, j4 = t & 3;
            *(float4*)&Qt[qi][j4 * 4] =
                *(const float4*)&Qf[(size_t)(b * Q8 + qi) * Np + m0 + j4 * 4];
        }
        {
            int c = t >> 2, j4 = t & 3;
            *(float4*)&Ut[c][j4 * 4] =
                *(const float4*)&Uf[(size_t)(b * Cc + c) * Np + m0 + j4 * 4];
        }
        __syncthreads();

        float p[TM];
        {
            float s[TM];
            #pragma unroll
            for (int j = 0; j < TM; j++) s[j] = 0.f;
            #pragma unroll
            for (int i = 0; i < Q8; i++) {
                const float4* q4 = (const float4*)&Qt[i][0];
                float ki = kn[i];
                #pragma unroll
                for (int j4 = 0; j4 < TM / 4; j4++) {
                    float4 qv = q4[j4];
                    s[j4 * 4 + 0] += ki * qv.x;
                    s[j4 * 4 + 1] += ki * qv.y;
                    s[j4 * 4 + 2] += ki * qv.z;
                    s[j4 * 4 + 3] += ki * qv.w;
                }
            }
            #pragma unroll
            for (int j = 0; j < TM; j++) p[j] = __expf(s[j]);
        }
        #pragma unroll
        for (int c = 0; c < Cc; c++) {
            const float4* u4 = (const float4*)&Ut[c][0];
            float a = acc[c];
            #pragma unroll
            for (int j4 = 0; j4 < TM / 4; j4++) {
                float4 uv = u4[j4];
                a += p[j4 * 4 + 0] * uv.x;
                a += p[j4 * 4 + 1] * uv.y;
                a += p[j4 * 4 + 2] * uv.z;
                a += p[j4 * 4 + 3] * uv.w;
            }
            acc[c] = a;
        }
    }
    float* po = PO + (size_t)((b * gridDim.y + slice) * Cc) * Np + n;
    #pragma unroll
    for (int c = 0; c < Cc; c++) po[(size_t)c * Np] = acc[c];
}

// ---------------- kernel 5: combine slices + gamma*out + x ----------------
__global__ __launch_bounds__(256) void combine_kernel(
    const float* __restrict__ PO, const float* __restrict__ x,
    const float* __restrict__ gamma, float* __restrict__ out, int sl2)
{
    int idx = blockIdx.x * 256 + threadIdx.x;  // over Bn*Cc*Np
    int b = idx >> 18;
    int c = (idx >> 12) & 63;
    int n = idx & (Np - 1);
    float o = 0.f;
    for (int sl = 0; sl < sl2; ++sl)
        o += PO[(size_t)((b * sl2 + sl) * Cc + c) * Np + n];
    out[idx] = gamma[0] * o + x[idx];
}

extern "C" void kernel_launch(void* const* d_in, const int* in_sizes, int n_in,
                              void* d_out, int out_size, void* d_ws, size_t ws_size,
                              hipStream_t stream)
{
    const float* x     = (const float*)d_in[0];
    const float* Wq    = (const float*)d_in[1];
    const float* bq    = (const float*)d_in[2];
    const float* Wk    = (const float*)d_in[3];
    const float* bk    = (const float*)d_in[4];
    const float* Wv    = (const float*)d_in[5];
    const float* bv    = (const float*)d_in[6];
    const float* gamma = (const float*)d_in[7];
    float* out = (float*)d_out;
    float* ws  = (float*)d_ws;

    float* Qf = ws;                                 // Bn*Q8*Np
    float* Kf = Qf + (size_t)Bn * Q8 * Np;          // Bn*Q8*Np
    float* Vf = Kf + (size_t)Bn * Q8 * Np;          // Bn*Cc*Np  (becomes U in place)
    float* ZP = Vf + (size_t)Bn * Cc * Np;          // Bn*SLZ*Np
    float* PO = ZP + (size_t)Bn * SLZ * Np;         // Bn*SL2*Cc*Np

    size_t base_floats = (size_t)Bn * Q8 * Np * 2 + (size_t)Bn * Cc * Np
                       + (size_t)Bn * SLZ * Np;     // 1,441,792 floats
    int SL2 = 8;
    while (SL2 > 1 &&
           (base_floats + (size_t)Bn * SL2 * Cc * Np) * sizeof(float) > ws_size)
        SL2 >>= 1;

    qkv_kernel<<<Bn * Np / 256, 256, 0, stream>>>(x, Wq, bq, Wk, bk, Wv, bv, Qf, Kf, Vf);
    zsum_kernel<<<dim3(Np / 256, SLZ, Bn), 256, 0, stream>>>(Qf, Kf, ZP, Np / SLZ);
    u_kernel<<<Bn * Np / 256, 256, 0, stream>>>(ZP, Vf);
    attn_kernel<<<dim3(Np / 256, SL2, Bn), 256, 0, stream>>>(Kf, Qf, Vf, PO, Np / SL2);
    combine_kernel<<<Bn * Cc * Np / 256, 256, 0, stream>>>(PO, x, gamma, out, SL2);
}

// Round 2
// 228.723 us; speedup vs baseline: 3.4267x; 3.4267x over previous
//
#include <hip/hip_runtime.h>

// SelfAttention (SAGAN-style), MI355X — bf16 MFMA implementation.
// Math: out[b,c,n] = gamma * sum_m exp(S[m,n]) * V[b,c,m] / Z[m] + x[b,c,n]
//   S[m,n] = sum_q Q[q,m] K[q,n],  Z[m] = sum_j exp(S[m,j]).
// Normalization folds into U = V/Z, so m-sliced partials combine by addition.
//
// MFMA shape: v_mfma_f32_16x16x32_bf16.
//   A-frag: A[i = lane&15][k = (lane>>4)*8 + j]   (8 bf16 / lane)
//   B-frag: B[k = (lane>>4)*8 + j][j = lane&15]
//   C/D:    col = lane&15, row = (lane>>4)*4 + reg
// Q/K stored bf16 as [pos][32] (q padded 8->32 with zeros) => frag-ready.
// U stored bf16 as [c][m] => A-frag-ready for the out GEMM.

constexpr int Bn = 4, Cc = 64, Q8 = 8, Np = 4096;
constexpr int NSL = 2;      // zsum n-slices
constexpr int QK_STR = 32;  // padded q dim (shorts) per position
constexpr int PSTR = 40;    // Plds row stride in shorts (32 m + 8 pad)

typedef float f32x4 __attribute__((ext_vector_type(4)));
typedef short short8 __attribute__((ext_vector_type(8)));

__device__ inline unsigned int f2bf(float x) {  // RNE f32->bf16 (as u16)
    unsigned int u = __float_as_uint(x);
    u += 0x7fff + ((u >> 16) & 1);
    return u >> 16;
}

// ---------------- kernel 1: QKV projections ----------------
__global__ __launch_bounds__(256) void qkv_kernel(
    const float* __restrict__ x,
    const float* __restrict__ Wq, const float* __restrict__ bq,
    const float* __restrict__ Wk, const float* __restrict__ bk,
    const float* __restrict__ Wv, const float* __restrict__ bv,
    unsigned short* __restrict__ Qp, unsigned short* __restrict__ Kp,
    float* __restrict__ Vf)
{
    __shared__ float sWqT[Cc * Q8];  // [c][o]
    __shared__ float sWkT[Cc * Q8];
    __shared__ float sWvT[Cc * Cc];
    int t = threadIdx.x;
    for (int idx = t; idx < Q8 * Cc; idx += 256) {
        int o = idx >> 6, c = idx & 63;
        sWqT[c * Q8 + o] = Wq[idx];
        sWkT[c * Q8 + o] = Wk[idx];
    }
    for (int idx = t; idx < Cc * Cc; idx += 256) {
        int o = idx >> 6, c = idx & 63;
        sWvT[c * Cc + o] = Wv[idx];
    }
    __syncthreads();

    int gid = blockIdx.x * 256 + t;  // over Bn*Np
    int b = gid >> 12, n = gid & (Np - 1);

    float q[Q8], k[Q8], v[Cc];
    #pragma unroll
    for (int i = 0; i < Q8; i++) { q[i] = bq[i]; k[i] = bk[i]; }
    #pragma unroll
    for (int i = 0; i < Cc; i++) v[i] = bv[i];

    const float* xp = x + (size_t)(b * Cc) * Np + n;
    for (int c = 0; c < Cc; c++) {
        float xv = xp[(size_t)c * Np];
        const float4* wq4 = (const float4*)&sWqT[c * Q8];
        float4 w0 = wq4[0], w1 = wq4[1];
        q[0] += w0.x * xv; q[1] += w0.y * xv; q[2] += w0.z * xv; q[3] += w0.w * xv;
        q[4] += w1.x * xv; q[5] += w1.y * xv; q[6] += w1.z * xv; q[7] += w1.w * xv;
        const float4* wk4 = (const float4*)&sWkT[c * Q8];
        w0 = wk4[0]; w1 = wk4[1];
        k[0] += w0.x * xv; k[1] += w0.y * xv; k[2] += w0.z * xv; k[3] += w0.w * xv;
        k[4] += w1.x * xv; k[5] += w1.y * xv; k[6] += w1.z * xv; k[7] += w1.w * xv;
        const float4* wv4 = (const float4*)&sWvT[c * Cc];
        #pragma unroll
        for (int i4 = 0; i4 < Cc / 4; i4++) {
            float4 w = wv4[i4];
            v[i4 * 4 + 0] += w.x * xv;
            v[i4 * 4 + 1] += w.y * xv;
            v[i4 * 4 + 2] += w.z * xv;
            v[i4 * 4 + 3] += w.w * xv;
        }
    }
    // bf16 padded rows [pos][32]
    uint4 qv, kv, z4;
    qv.x = f2bf(q[0]) | (f2bf(q[1]) << 16); qv.y = f2bf(q[2]) | (f2bf(q[3]) << 16);
    qv.z = f2bf(q[4]) | (f2bf(q[5]) << 16); qv.w = f2bf(q[6]) | (f2bf(q[7]) << 16);
    kv.x = f2bf(k[0]) | (f2bf(k[1]) << 16); kv.y = f2bf(k[2]) | (f2bf(k[3]) << 16);
    kv.z = f2bf(k[4]) | (f2bf(k[5]) << 16); kv.w = f2bf(k[6]) | (f2bf(k[7]) << 16);
    z4 = make_uint4(0, 0, 0, 0);
    unsigned short* qrow = Qp + (size_t)(b * Np + n) * QK_STR;
    unsigned short* krow = Kp + (size_t)(b * Np + n) * QK_STR;
    *(uint4*)(qrow) = qv; *(uint4*)(qrow + 8) = z4;
    *(uint4*)(qrow + 16) = z4; *(uint4*)(qrow + 24) = z4;
    *(uint4*)(krow) = kv; *(uint4*)(krow + 8) = z4;
    *(uint4*)(krow + 16) = z4; *(uint4*)(krow + 24) = z4;
    #pragma unroll
    for (int i = 0; i < Cc; i++) Vf[(size_t)(b * Cc + i) * Np + n] = v[i];
}

// ---------------- kernel 2: Z[m] via MFMA ----------------
__global__ __launch_bounds__(256) void zsum_mfma(
    const unsigned short* __restrict__ Qp, const unsigned short* __restrict__ Kp,
    float* __restrict__ ZP)
{
    const int tid = threadIdx.x, w = tid >> 6, lane = tid & 63;
    const int quad = lane >> 4, l15 = lane & 15;
    const int bz = blockIdx.z, ns = blockIdx.y;
    const int m0 = blockIdx.x * 64 + w * 16;

    short8 qa = *(const short8*)&Qp[((size_t)(bz * Np + m0 + l15)) * QK_STR + quad * 8];
    float z0 = 0.f, z1 = 0.f, z2 = 0.f, z3 = 0.f;
    const int n_base = ns * (Np / NSL);
    for (int nt = 0; nt < Np / NSL; nt += 16) {
        int n = n_base + nt + l15;
        short8 kb = *(const short8*)&Kp[((size_t)(bz * Np + n)) * QK_STR + quad * 8];
        f32x4 s = __builtin_amdgcn_mfma_f32_16x16x32_bf16(
            qa, kb, f32x4{0.f, 0.f, 0.f, 0.f}, 0, 0, 0);
        z0 += __expf(s[0]); z1 += __expf(s[1]); z2 += __expf(s[2]); z3 += __expf(s[3]);
    }
    #pragma unroll
    for (int mask = 1; mask < 16; mask <<= 1) {
        z0 += __shfl_xor(z0, mask); z1 += __shfl_xor(z1, mask);
        z2 += __shfl_xor(z2, mask); z3 += __shfl_xor(z3, mask);
    }
    if (l15 == 0) {
        float4 v = make_float4(z0, z1, z2, z3);
        *(float4*)&ZP[((size_t)(bz * NSL + ns)) * Np + m0 + quad * 4] = v;
    }
}

// ---------------- kernel 3: U = bf16(V / Z) ----------------
__global__ __launch_bounds__(256) void u_kernel(
    const float* __restrict__ ZP, const float* __restrict__ Vf,
    unsigned short* __restrict__ Ub)
{
    int gid = blockIdx.x * 256 + threadIdx.x;  // over Bn*Np
    int b = gid >> 12, m = gid & (Np - 1);
    float z = 0.f;
    #pragma unroll
    for (int s = 0; s < NSL; s++) z += ZP[((size_t)(b * NSL + s)) * Np + m];
    float zi = 1.f / z;
    const float* vp = Vf + (size_t)(b * Cc) * Np + m;
    unsigned short* up = Ub + (size_t)(b * Cc) * Np + m;
    #pragma unroll
    for (int c = 0; c < Cc; c++)
        up[(size_t)c * Np] = (unsigned short)f2bf(vp[(size_t)c * Np] * zi);
}

// ---------------- kernel 4: out partials via MFMA, barrier-free ----------------
__global__ __launch_bounds__(256) void attn_mfma(
    const unsigned short* __restrict__ Qp, const unsigned short* __restrict__ Kp,
    const unsigned short* __restrict__ Ub, float* __restrict__ PO, int Ms, int SL)
{
    __shared__ unsigned short Plds[128 * PSTR];  // [n_local][m_local], wave-private rows
    const int tid = threadIdx.x, w = tid >> 6, lane = tid & 63;
    const int quad = lane >> 4, l15 = lane & 15;
    const int bz = blockIdx.z, by = blockIdx.y, nb = blockIdx.x * 128;

    // loop-invariant K B-frags for this wave's two 16-n subtiles
    short8 kf[2];
    #pragma unroll
    for (int t = 0; t < 2; t++) {
        int n = nb + (2 * w + t) * 16 + l15;
        kf[t] = *(const short8*)&Kp[((size_t)(bz * Np + n)) * QK_STR + quad * 8];
    }
    f32x4 acc[4][2];
    #pragma unroll
    for (int ct = 0; ct < 4; ct++)
        #pragma unroll
        for (int t = 0; t < 2; t++) acc[ct][t] = f32x4{0.f, 0.f, 0.f, 0.f};

    const int m_base = by * Ms;
    for (int mi = 0; mi < Ms; mi += 32) {
        const int m0 = m_base + mi;
        // phase 1: P[m0..m0+31][this wave's 32 n] = exp(S), bf16, into LDS
        #pragma unroll
        for (int mt = 0; mt < 2; mt++) {
            short8 qa = *(const short8*)
                &Qp[((size_t)(bz * Np + m0 + mt * 16 + l15)) * QK_STR + quad * 8];
            #pragma unroll
            for (int t = 0; t < 2; t++) {
                f32x4 s = __builtin_amdgcn_mfma_f32_16x16x32_bf16(
                    qa, kf[t], f32x4{0.f, 0.f, 0.f, 0.f}, 0, 0, 0);
                unsigned e0 = f2bf(__expf(s[0])), e1 = f2bf(__expf(s[1]));
                unsigned e2 = f2bf(__expf(s[2])), e3 = f2bf(__expf(s[3]));
                int nl = (2 * w + t) * 16 + l15;
                *(uint2*)&Plds[nl * PSTR + mt * 16 + quad * 4] =
                    make_uint2(e0 | (e1 << 16), e2 | (e3 << 16));
            }
        }
        // phase 2: acc[c, n] += U[c, m0..31] * P[m0..31, n] (wave-private LDS rows)
        short8 pb[2];
        #pragma unroll
        for (int t = 0; t < 2; t++)
            pb[t] = *(const short8*)&Plds[(w * 32 + t * 16 + l15) * PSTR + quad * 8];
        #pragma unroll
        for (int ct = 0; ct < 4; ct++) {
            short8 ua = *(const short8*)
                &Ub[((size_t)(bz * Cc + ct * 16 + l15)) * Np + m0 + quad * 8];
            #pragma unroll
            for (int t = 0; t < 2; t++)
                acc[ct][t] = __builtin_amdgcn_mfma_f32_16x16x32_bf16(
                    ua, pb[t], acc[ct][t], 0, 0, 0);
        }
    }
    float* po = PO + ((size_t)((bz * SL + by) * Cc)) * Np + nb;
    #pragma unroll
    for (int ct = 0; ct < 4; ct++)
        #pragma unroll
        for (int t = 0; t < 2; t++) {
            int c = ct * 16 + quad * 4, n = w * 32 + t * 16 + l15;
            #pragma unroll
            for (int r = 0; r < 4; r++)
                po[(size_t)(c + r) * Np + n] = acc[ct][t][r];
        }
}

// ---------------- kernel 5: combine slices + gamma*out + x ----------------
__global__ __launch_bounds__(256) void combine_kernel(
    const float* __restrict__ PO, const float* __restrict__ x,
    const float* __restrict__ gamma, float* __restrict__ out, int sl2)
{
    int idx = blockIdx.x * 256 + threadIdx.x;  // over Bn*Cc*Np
    int b = idx >> 18;
    int c = (idx >> 12) & 63;
    int n = idx & (Np - 1);
    float o = 0.f;
    for (int sl = 0; sl < sl2; ++sl)
        o += PO[(size_t)((b * sl2 + sl) * Cc + c) * Np + n];
    out[idx] = gamma[0] * o + x[idx];
}

extern "C" void kernel_launch(void* const* d_in, const int* in_sizes, int n_in,
                              void* d_out, int out_size, void* d_ws, size_t ws_size,
                              hipStream_t stream)
{
    const float* x     = (const float*)d_in[0];
    const float* Wq    = (const float*)d_in[1];
    const float* bq    = (const float*)d_in[2];
    const float* Wk    = (const float*)d_in[3];
    const float* bk    = (const float*)d_in[4];
    const float* Wv    = (const float*)d_in[5];
    const float* bv    = (const float*)d_in[6];
    const float* gamma = (const float*)d_in[7];
    float* out = (float*)d_out;

    unsigned short* Qp = (unsigned short*)d_ws;               // Bn*Np*32 bf16 = 1 MB
    unsigned short* Kp = Qp + (size_t)Bn * Np * QK_STR;       // 1 MB
    float* Vf = (float*)(Kp + (size_t)Bn * Np * QK_STR);      // Bn*Cc*Np f32 = 4 MB
    unsigned short* Ub = (unsigned short*)(Vf + (size_t)Bn * Cc * Np);  // 2 MB
    float* ZP = (float*)(Ub + (size_t)Bn * Cc * Np);          // Bn*NSL*Np f32
    float* PO = ZP + (size_t)Bn * NSL * Np;                   // Bn*SL*Cc*Np f32

    size_t baseB = (size_t)Bn * Np * QK_STR * 2 * 2 + (size_t)Bn * Cc * Np * 4
                 + (size_t)Bn * Cc * Np * 2 + (size_t)Bn * NSL * Np * 4;
    int SL = 4;  // m-slices for attn partials
    while (SL > 1 && baseB + (size_t)Bn * SL * Cc * Np * 4 > ws_size) SL >>= 1;

    qkv_kernel<<<Bn * Np / 256, 256, 0, stream>>>(x, Wq, bq, Wk, bk, Wv, bv, Qp, Kp, Vf);
    zsum_mfma<<<dim3(Np / 64, NSL, Bn), 256, 0, stream>>>(Qp, Kp, ZP);
    u_kernel<<<Bn * Np / 256, 256, 0, stream>>>(ZP, Vf, Ub);
    attn_mfma<<<dim3(Np / 128, SL, Bn), 256, 0, stream>>>(Qp, Kp, Ub, PO, Np / SL, SL);
    combine_kernel<<<Bn * Cc * Np / 256, 256, 0, stream>>>(PO, x, gamma, out, SL);
}

// Round 3
// 211.761 us; speedup vs baseline: 3.7012x; 1.0801x over previous
//
#include <hip/hip_runtime.h>

// SelfAttention (SAGAN-style), MI355X — bf16 MFMA implementation, v3.
// Math: out[b,c,n] = gamma * sum_m [exp(S[m,n]) / Z[m]] * V[b,c,m] + x[b,c,n]
//   S[m,n] = sum_q Q[q,m] K[q,n],  Z[m] = sum_j exp(S[m,j]).
// Normalization folds into P[m,n] = exp(S)·Zinv[m]; m-sliced partials add.
//
// MFMA shape: v_mfma_f32_16x16x32_bf16.
//   A-frag: A[i = lane&15][k = (lane>>4)*8 + j]
//   B-frag: B[k = (lane>>4)*8 + j][j = lane&15]
//   C/D:    col = lane&15, row = (lane>>4)*4 + reg

constexpr int Bn = 4, Cc = 64, Q8 = 8, Np = 4096;
constexpr int QK_STR = 32;  // padded q dim (shorts) per position
constexpr int PSTR = 40;    // Plds row stride in shorts (32 m + 8 pad)

typedef float f32x4 __attribute__((ext_vector_type(4)));
typedef short short8 __attribute__((ext_vector_type(8)));

__device__ inline unsigned int f2bf(float x) {  // RNE f32->bf16 (as u16)
    unsigned int u = __float_as_uint(x);
    u += 0x7fff + ((u >> 16) & 1);
    return u >> 16;
}
__device__ inline float bf2f(unsigned int u) { return __uint_as_float(u << 16); }

// ---------------- kernel 1: QKV projections, lane-per-position ----------------
// grid (Bn*Np/64, 4), block 64. blockIdx.y = output slice (20 rows of W each):
//   slice 0: Q rows 0..7, K rows 0..7, V rows 0..3
//   slice s>=1: V rows 20s-16 .. 20s+3
__global__ __launch_bounds__(64) void qkv_v2(
    const float* __restrict__ x,
    const float* __restrict__ Wq, const float* __restrict__ bq,
    const float* __restrict__ Wk, const float* __restrict__ bk,
    const float* __restrict__ Wv, const float* __restrict__ bv,
    unsigned short* __restrict__ Qp, unsigned short* __restrict__ Kp,
    unsigned short* __restrict__ Vb)
{
    const int lane = threadIdx.x;
    const int gpos = blockIdx.x * 64;        // over Bn*Np
    const int os = blockIdx.y;               // uniform -> scalar W loads
    const int b = gpos >> 12, n = (gpos & (Np - 1)) + lane;

    // this lane's x column (64 channels) in VGPRs; loads are 256B-coalesced
    float xv[Cc];
    const float* xp = x + (size_t)(b * Cc) * Np + n;
    #pragma unroll
    for (int c = 0; c < Cc; c++) xv[c] = xp[(size_t)c * Np];

    if (os == 0) {
        unsigned pk[4];
        // Q rows 0..7 -> bf16 packed row [n][32] with zero padding
        float a0, a1;
        #pragma unroll
        for (int p = 0; p < 4; p++) {
            a0 = bq[2 * p]; a1 = bq[2 * p + 1];
            #pragma unroll
            for (int c = 0; c < Cc; c++) {
                a0 += Wq[(2 * p) * Cc + c] * xv[c];
                a1 += Wq[(2 * p + 1) * Cc + c] * xv[c];
            }
            pk[p] = f2bf(a0) | (f2bf(a1) << 16);
        }
        unsigned short* qrow = Qp + (size_t)(b * Np + n) * QK_STR;
        *(uint4*)qrow = make_uint4(pk[0], pk[1], pk[2], pk[3]);
        *(uint4*)(qrow + 8)  = make_uint4(0, 0, 0, 0);
        *(uint4*)(qrow + 16) = make_uint4(0, 0, 0, 0);
        *(uint4*)(qrow + 24) = make_uint4(0, 0, 0, 0);
        // K rows 0..7
        #pragma unroll
        for (int p = 0; p < 4; p++) {
            a0 = bk[2 * p]; a1 = bk[2 * p + 1];
            #pragma unroll
            for (int c = 0; c < Cc; c++) {
                a0 += Wk[(2 * p) * Cc + c] * xv[c];
                a1 += Wk[(2 * p + 1) * Cc + c] * xv[c];
            }
            pk[p] = f2bf(a0) | (f2bf(a1) << 16);
        }
        unsigned short* krow = Kp + (size_t)(b * Np + n) * QK_STR;
        *(uint4*)krow = make_uint4(pk[0], pk[1], pk[2], pk[3]);
        *(uint4*)(krow + 8)  = make_uint4(0, 0, 0, 0);
        *(uint4*)(krow + 16) = make_uint4(0, 0, 0, 0);
        *(uint4*)(krow + 24) = make_uint4(0, 0, 0, 0);
        // V rows 0..3
        #pragma unroll
        for (int o = 0; o < 4; o++) {
            float a = bv[o];
            #pragma unroll
            for (int c = 0; c < Cc; c++) a += Wv[o * Cc + c] * xv[c];
            Vb[(size_t)(b * Cc + o) * Np + n] = (unsigned short)f2bf(a);
        }
    } else {
        const int vbase = os * 20 - 16;      // 4, 24, 44
        #pragma unroll 4
        for (int o = 0; o < 20; o++) {
            const int vr = vbase + o;
            float a = bv[vr];
            #pragma unroll
            for (int c = 0; c < Cc; c++) a += Wv[vr * Cc + c] * xv[c];
            Vb[(size_t)(b * Cc + vr) * Np + n] = (unsigned short)f2bf(a);
        }
    }
}

// ---------------- kernel 2: Zinv[m] = 1 / sum_n exp(Q_m . K_n), via MFMA ----------------
__global__ __launch_bounds__(256) void zsum_mfma(
    const unsigned short* __restrict__ Qp, const unsigned short* __restrict__ Kp,
    float* __restrict__ Zinv)
{
    const int tid = threadIdx.x, w = tid >> 6, lane = tid & 63;
    const int quad = lane >> 4, l15 = lane & 15;
    const int bz = blockIdx.z;
    const int m0 = blockIdx.x * 64 + w * 16;

    short8 qa = *(const short8*)&Qp[((size_t)(bz * Np + m0 + l15)) * QK_STR + quad * 8];
    float z0 = 0.f, z1 = 0.f, z2 = 0.f, z3 = 0.f;
    for (int nt = 0; nt < Np; nt += 16) {
        int n = nt + l15;
        short8 kb = *(const short8*)&Kp[((size_t)(bz * Np + n)) * QK_STR + quad * 8];
        f32x4 s = __builtin_amdgcn_mfma_f32_16x16x32_bf16(
            qa, kb, f32x4{0.f, 0.f, 0.f, 0.f}, 0, 0, 0);
        z0 += __expf(s[0]); z1 += __expf(s[1]); z2 += __expf(s[2]); z3 += __expf(s[3]);
    }
    #pragma unroll
    for (int mask = 1; mask < 16; mask <<= 1) {
        z0 += __shfl_xor(z0, mask); z1 += __shfl_xor(z1, mask);
        z2 += __shfl_xor(z2, mask); z3 += __shfl_xor(z3, mask);
    }
    if (l15 == 0) {
        float4 v = make_float4(1.f / z0, 1.f / z1, 1.f / z2, 1.f / z3);
        *(float4*)&Zinv[(size_t)bz * Np + m0 + quad * 4] = v;
    }
}

// ---------------- kernel 3: out partials via MFMA, barrier-free ----------------
__global__ __launch_bounds__(256) void attn_mfma(
    const unsigned short* __restrict__ Qp, const unsigned short* __restrict__ Kp,
    const unsigned short* __restrict__ Vb, const float* __restrict__ Zinv,
    unsigned short* __restrict__ PO, int Ms, int SL)
{
    __shared__ unsigned short Plds[128 * PSTR];  // [n_local][m_local], wave-private rows
    const int tid = threadIdx.x, w = tid >> 6, lane = tid & 63;
    const int quad = lane >> 4, l15 = lane & 15;
    const int bz = blockIdx.z, by = blockIdx.y, nb = blockIdx.x * 128;

    // loop-invariant K B-frags for this wave's two 16-n subtiles
    short8 kf[2];
    #pragma unroll
    for (int t = 0; t < 2; t++) {
        int n = nb + (2 * w + t) * 16 + l15;
        kf[t] = *(const short8*)&Kp[((size_t)(bz * Np + n)) * QK_STR + quad * 8];
    }
    f32x4 acc[4][2];
    #pragma unroll
    for (int ct = 0; ct < 4; ct++)
        #pragma unroll
        for (int t = 0; t < 2; t++) acc[ct][t] = f32x4{0.f, 0.f, 0.f, 0.f};

    const int m_base = by * Ms;
    for (int mi = 0; mi < Ms; mi += 32) {
        const int m0 = m_base + mi;
        // phase 1: P[m0..m0+31][this wave's 32 n] = exp(S)*Zinv[m], bf16, into LDS
        #pragma unroll
        for (int mt = 0; mt < 2; mt++) {
            short8 qa = *(const short8*)
                &Qp[((size_t)(bz * Np + m0 + mt * 16 + l15)) * QK_STR + quad * 8];
            float4 zi = *(const float4*)
                &Zinv[(size_t)bz * Np + m0 + mt * 16 + quad * 4];
            #pragma unroll
            for (int t = 0; t < 2; t++) {
                f32x4 s = __builtin_amdgcn_mfma_f32_16x16x32_bf16(
                    qa, kf[t], f32x4{0.f, 0.f, 0.f, 0.f}, 0, 0, 0);
                unsigned e0 = f2bf(__expf(s[0]) * zi.x), e1 = f2bf(__expf(s[1]) * zi.y);
                unsigned e2 = f2bf(__expf(s[2]) * zi.z), e3 = f2bf(__expf(s[3]) * zi.w);
                int nl = (2 * w + t) * 16 + l15;
                *(uint2*)&Plds[nl * PSTR + mt * 16 + quad * 4] =
                    make_uint2(e0 | (e1 << 16), e2 | (e3 << 16));
            }
        }
        // phase 2: acc[c, n] += V[c, m0..31] * P[m0..31, n] (wave-private LDS rows)
        short8 pb[2];
        #pragma unroll
        for (int t = 0; t < 2; t++)
            pb[t] = *(const short8*)&Plds[(w * 32 + t * 16 + l15) * PSTR + quad * 8];
        #pragma unroll
        for (int ct = 0; ct < 4; ct++) {
            short8 ua = *(const short8*)
                &Vb[((size_t)(bz * Cc + ct * 16 + l15)) * Np + m0 + quad * 8];
            #pragma unroll
            for (int t = 0; t < 2; t++)
                acc[ct][t] = __builtin_amdgcn_mfma_f32_16x16x32_bf16(
                    ua, pb[t], acc[ct][t], 0, 0, 0);
        }
    }
    unsigned short* po = PO + ((size_t)((bz * SL + by) * Cc)) * Np + nb;
    #pragma unroll
    for (int ct = 0; ct < 4; ct++)
        #pragma unroll
        for (int t = 0; t < 2; t++) {
            int c = ct * 16 + quad * 4, n = w * 32 + t * 16 + l15;
            #pragma unroll
            for (int r = 0; r < 4; r++)
                po[(size_t)(c + r) * Np + n] = (unsigned short)f2bf(acc[ct][t][r]);
        }
}

// ---------------- kernel 4: combine slices + gamma*out + x (8-wide) ----------------
__global__ __launch_bounds__(256) void combine_kernel(
    const unsigned short* __restrict__ PO, const float* __restrict__ x,
    const float* __restrict__ gamma, float* __restrict__ out, int sl2)
{
    int idx8 = (blockIdx.x * 256 + threadIdx.x) * 8;  // over Bn*Cc*Np
    int b = idx8 >> 18;
    int c = (idx8 >> 12) & 63;
    int n = idx8 & (Np - 1);
    float o[8];
    #pragma unroll
    for (int i = 0; i < 8; i++) o[i] = 0.f;
    for (int sl = 0; sl < sl2; ++sl) {
        uint4 u = *(const uint4*)&PO[(size_t)((b * sl2 + sl) * Cc + c) * Np + n];
        o[0] += bf2f(u.x & 0xffff); o[1] += bf2f(u.x >> 16);
        o[2] += bf2f(u.y & 0xffff); o[3] += bf2f(u.y >> 16);
        o[4] += bf2f(u.z & 0xffff); o[5] += bf2f(u.z >> 16);
        o[6] += bf2f(u.w & 0xffff); o[7] += bf2f(u.w >> 16);
    }
    float g = gamma[0];
    float4 x0 = *(const float4*)&x[idx8];
    float4 x1 = *(const float4*)&x[idx8 + 4];
    float4 r0 = make_float4(g * o[0] + x0.x, g * o[1] + x0.y,
                            g * o[2] + x0.z, g * o[3] + x0.w);
    float4 r1 = make_float4(g * o[4] + x1.x, g * o[5] + x1.y,
                            g * o[6] + x1.z, g * o[7] + x1.w);
    *(float4*)&out[idx8] = r0;
    *(float4*)&out[idx8 + 4] = r1;
}

extern "C" void kernel_launch(void* const* d_in, const int* in_sizes, int n_in,
                              void* d_out, int out_size, void* d_ws, size_t ws_size,
                              hipStream_t stream)
{
    const float* x     = (const float*)d_in[0];
    const float* Wq    = (const float*)d_in[1];
    const float* bq    = (const float*)d_in[2];
    const float* Wk    = (const float*)d_in[3];
    const float* bk    = (const float*)d_in[4];
    const float* Wv    = (const float*)d_in[5];
    const float* bv    = (const float*)d_in[6];
    const float* gamma = (const float*)d_in[7];
    float* out = (float*)d_out;

    unsigned short* Qp = (unsigned short*)d_ws;               // 1 MB
    unsigned short* Kp = Qp + (size_t)Bn * Np * QK_STR;       // 1 MB
    unsigned short* Vb = Kp + (size_t)Bn * Np * QK_STR;       // 2 MB (bf16 V, unnormalized)
    float* Zinv = (float*)(Vb + (size_t)Bn * Cc * Np);        // 64 KB
    unsigned short* PO = (unsigned short*)(Zinv + (size_t)Bn * Np);  // SL * 2 MB

    size_t baseB = (size_t)Bn * Np * QK_STR * 2 * 2 + (size_t)Bn * Cc * Np * 2
                 + (size_t)Bn * Np * 4;
    int SL = 4;  // m-slices for attn partials
    while (SL > 1 && baseB + (size_t)Bn * SL * Cc * Np * 2 > ws_size) SL >>= 1;

    qkv_v2<<<dim3(Bn * Np / 64, 4), 64, 0, stream>>>(x, Wq, bq, Wk, bk, Wv, bv,
                                                     Qp, Kp, Vb);
    zsum_mfma<<<dim3(Np / 64, 1, Bn), 256, 0, stream>>>(Qp, Kp, Zinv);
    attn_mfma<<<dim3(Np / 128, SL, Bn), 256, 0, stream>>>(Qp, Kp, Vb, Zinv,
                                                          PO, Np / SL, SL);
    combine_kernel<<<Bn * Cc * Np / (256 * 8), 256, 0, stream>>>(PO, x, gamma, out, SL);
}

// Round 4
// 149.374 us; speedup vs baseline: 5.2470x; 1.4177x over previous
//
#include <hip/hip_runtime.h>

// SelfAttention (SAGAN-style), MI355X — bf16 MFMA implementation, v4.
// Math: out[b,c,n] = gamma * sum_m [exp(S[m,n]) / Z[m]] * V[b,c,m] + x[b,c,n]
//   S[m,n] = sum_q Q[q,m] K[q,n],  Z[m] = sum_j exp(S[m,j]).
// Normalization folds into P[m,n] = exp(S)·Zinv[m]; m-sliced partials add.
//
// MFMA shape: v_mfma_f32_16x16x32_bf16.
//   A-frag: A[i = lane&15][k = (lane>>4)*8 + j]
//   B-frag: B[k = (lane>>4)*8 + j][j = lane&15]
//   C/D:    col = lane&15, row = (lane>>4)*4 + reg

constexpr int Bn = 4, Cc = 64, Q8 = 8, Np = 4096;
constexpr int QK_STR = 32;  // padded q dim (shorts) per position
constexpr int PSTR = 40;    // attn Plds row stride in shorts (32 m + 8 pad)
constexpr int NSL = 4;      // zsum n-slices
constexpr int KSTR = 40;    // zsum Klds row stride in shorts (32 + 8 pad)

typedef float f32x4 __attribute__((ext_vector_type(4)));
typedef short short8 __attribute__((ext_vector_type(8)));

__device__ inline unsigned int f2bf(float x) {  // RNE f32->bf16 (as u16)
    unsigned int u = __float_as_uint(x);
    u += 0x7fff + ((u >> 16) & 1);
    return u >> 16;
}
__device__ inline float bf2f(unsigned int u) { return __uint_as_float(u << 16); }

// ---------------- kernel 1: QKV projections, lane-per-position ----------------
__global__ __launch_bounds__(64) void qkv_v2(
    const float* __restrict__ x,
    const float* __restrict__ Wq, const float* __restrict__ bq,
    const float* __restrict__ Wk, const float* __restrict__ bk,
    const float* __restrict__ Wv, const float* __restrict__ bv,
    unsigned short* __restrict__ Qp, unsigned short* __restrict__ Kp,
    unsigned short* __restrict__ Vb)
{
    const int lane = threadIdx.x;
    const int gpos = blockIdx.x * 64;        // over Bn*Np
    const int os = blockIdx.y;               // uniform -> scalar W loads
    const int b = gpos >> 12, n = (gpos & (Np - 1)) + lane;

    float xv[Cc];
    const float* xp = x + (size_t)(b * Cc) * Np + n;
    #pragma unroll
    for (int c = 0; c < Cc; c++) xv[c] = xp[(size_t)c * Np];

    if (os == 0) {
        unsigned pk[4];
        float a0, a1;
        #pragma unroll
        for (int p = 0; p < 4; p++) {
            a0 = bq[2 * p]; a1 = bq[2 * p + 1];
            #pragma unroll
            for (int c = 0; c < Cc; c++) {
                a0 += Wq[(2 * p) * Cc + c] * xv[c];
                a1 += Wq[(2 * p + 1) * Cc + c] * xv[c];
            }
            pk[p] = f2bf(a0) | (f2bf(a1) << 16);
        }
        unsigned short* qrow = Qp + (size_t)(b * Np + n) * QK_STR;
        *(uint4*)qrow = make_uint4(pk[0], pk[1], pk[2], pk[3]);
        *(uint4*)(qrow + 8)  = make_uint4(0, 0, 0, 0);
        *(uint4*)(qrow + 16) = make_uint4(0, 0, 0, 0);
        *(uint4*)(qrow + 24) = make_uint4(0, 0, 0, 0);
        #pragma unroll
        for (int p = 0; p < 4; p++) {
            a0 = bk[2 * p]; a1 = bk[2 * p + 1];
            #pragma unroll
            for (int c = 0; c < Cc; c++) {
                a0 += Wk[(2 * p) * Cc + c] * xv[c];
                a1 += Wk[(2 * p + 1) * Cc + c] * xv[c];
            }
            pk[p] = f2bf(a0) | (f2bf(a1) << 16);
        }
        unsigned short* krow = Kp + (size_t)(b * Np + n) * QK_STR;
        *(uint4*)krow = make_uint4(pk[0], pk[1], pk[2], pk[3]);
        *(uint4*)(krow + 8)  = make_uint4(0, 0, 0, 0);
        *(uint4*)(krow + 16) = make_uint4(0, 0, 0, 0);
        *(uint4*)(krow + 24) = make_uint4(0, 0, 0, 0);
        #pragma unroll
        for (int o = 0; o < 4; o++) {
            float a = bv[o];
            #pragma unroll
            for (int c = 0; c < Cc; c++) a += Wv[o * Cc + c] * xv[c];
            Vb[(size_t)(b * Cc + o) * Np + n] = (unsigned short)f2bf(a);
        }
    } else {
        const int vbase = os * 20 - 16;      // 4, 24, 44
        #pragma unroll 4
        for (int o = 0; o < 20; o++) {
            const int vr = vbase + o;
            float a = bv[vr];
            #pragma unroll
            for (int c = 0; c < Cc; c++) a += Wv[vr * Cc + c] * xv[c];
            Vb[(size_t)(b * Cc + vr) * Np + n] = (unsigned short)f2bf(a);
        }
    }
}

// ---------------- kernel 2: Z partials via MFMA + shared LDS K stream ----------------
// grid (Np/64, NSL, Bn), block 256 (4 waves). Wave w: m-tile m0 = bx*64 + w*16.
// K tile [64][32] staged once per block into LDS, shared by all 4 waves.
__global__ __launch_bounds__(256) void zsum_v2(
    const unsigned short* __restrict__ Qp, const unsigned short* __restrict__ Kp,
    float* __restrict__ ZP)
{
    __shared__ unsigned short Klds[64 * KSTR];
    const int tid = threadIdx.x, w = tid >> 6, lane = tid & 63;
    const int quad = lane >> 4, l15 = lane & 15;
    const int bz = blockIdx.z, ns = blockIdx.y;
    const int m0 = blockIdx.x * 64 + w * 16;

    short8 qa = *(const short8*)&Qp[((size_t)(bz * Np + m0 + l15)) * QK_STR + quad * 8];

    const int rt = tid >> 2, ct = tid & 3;   // staging: row rt, 8-short chunk ct
    const int nbase = ns * (Np / NSL);
    const unsigned short* kbase = Kp + (size_t)bz * Np * QK_STR;

    uint4 pf = *(const uint4*)&kbase[(size_t)(nbase + rt) * QK_STR + ct * 8];
    float z0 = 0.f, z1 = 0.f, z2 = 0.f, z3 = 0.f;
    for (int nt = 0; nt < Np / NSL; nt += 64) {
        *(uint4*)&Klds[rt * KSTR + ct * 8] = pf;
        __syncthreads();
        if (nt + 64 < Np / NSL)
            pf = *(const uint4*)&kbase[(size_t)(nbase + nt + 64 + rt) * QK_STR + ct * 8];
        #pragma unroll
        for (int t16 = 0; t16 < 4; t16++) {
            short8 kb = *(const short8*)&Klds[(t16 * 16 + l15) * KSTR + quad * 8];
            f32x4 s = __builtin_amdgcn_mfma_f32_16x16x32_bf16(
                qa, kb, f32x4{0.f, 0.f, 0.f, 0.f}, 0, 0, 0);
            z0 += __expf(s[0]); z1 += __expf(s[1]);
            z2 += __expf(s[2]); z3 += __expf(s[3]);
        }
        __syncthreads();
    }
    #pragma unroll
    for (int mask = 1; mask < 16; mask <<= 1) {
        z0 += __shfl_xor(z0, mask); z1 += __shfl_xor(z1, mask);
        z2 += __shfl_xor(z2, mask); z3 += __shfl_xor(z3, mask);
    }
    if (l15 == 0) {
        float4 v = make_float4(z0, z1, z2, z3);
        *(float4*)&ZP[((size_t)(bz * NSL + ns)) * Np + m0 + quad * 4] = v;
    }
}

// ---------------- kernel 3: Zinv = 1 / sum of partials ----------------
__global__ __launch_bounds__(256) void zred(
    const float* __restrict__ ZP, float* __restrict__ Zinv)
{
    int i = blockIdx.x * 256 + threadIdx.x;  // over Bn*Np
    int b = i >> 12, m = i & (Np - 1);
    float z = 0.f;
    #pragma unroll
    for (int s = 0; s < NSL; s++) z += ZP[((size_t)(b * NSL + s)) * Np + m];
    Zinv[(size_t)b * Np + m] = 1.f / z;
}

// ---------------- kernel 4: out partials via MFMA, barrier-free ----------------
__global__ __launch_bounds__(256) void attn_mfma(
    const unsigned short* __restrict__ Qp, const unsigned short* __restrict__ Kp,
    const unsigned short* __restrict__ Vb, const float* __restrict__ Zinv,
    unsigned short* __restrict__ PO, int Ms, int SL)
{
    __shared__ unsigned short Plds[128 * PSTR];  // [n_local][m_local], wave-private rows
    const int tid = threadIdx.x, w = tid >> 6, lane = tid & 63;
    const int quad = lane >> 4, l15 = lane & 15;
    const int bz = blockIdx.z, by = blockIdx.y, nb = blockIdx.x * 128;

    short8 kf[2];
    #pragma unroll
    for (int t = 0; t < 2; t++) {
        int n = nb + (2 * w + t) * 16 + l15;
        kf[t] = *(const short8*)&Kp[((size_t)(bz * Np + n)) * QK_STR + quad * 8];
    }
    f32x4 acc[4][2];
    #pragma unroll
    for (int ct = 0; ct < 4; ct++)
        #pragma unroll
        for (int t = 0; t < 2; t++) acc[ct][t] = f32x4{0.f, 0.f, 0.f, 0.f};

    const int m_base = by * Ms;
    for (int mi = 0; mi < Ms; mi += 32) {
        const int m0 = m_base + mi;
        #pragma unroll
        for (int mt = 0; mt < 2; mt++) {
            short8 qa = *(const short8*)
                &Qp[((size_t)(bz * Np + m0 + mt * 16 + l15)) * QK_STR + quad * 8];
            float4 zi = *(const float4*)
                &Zinv[(size_t)bz * Np + m0 + mt * 16 + quad * 4];
            #pragma unroll
            for (int t = 0; t < 2; t++) {
                f32x4 s = __builtin_amdgcn_mfma_f32_16x16x32_bf16(
                    qa, kf[t], f32x4{0.f, 0.f, 0.f, 0.f}, 0, 0, 0);
                unsigned e0 = f2bf(__expf(s[0]) * zi.x), e1 = f2bf(__expf(s[1]) * zi.y);
                unsigned e2 = f2bf(__expf(s[2]) * zi.z), e3 = f2bf(__expf(s[3]) * zi.w);
                int nl = (2 * w + t) * 16 + l15;
                *(uint2*)&Plds[nl * PSTR + mt * 16 + quad * 4] =
                    make_uint2(e0 | (e1 << 16), e2 | (e3 << 16));
            }
        }
        short8 pb[2];
        #pragma unroll
        for (int t = 0; t < 2; t++)
            pb[t] = *(const short8*)&Plds[(w * 32 + t * 16 + l15) * PSTR + quad * 8];
        #pragma unroll
        for (int ct = 0; ct < 4; ct++) {
            short8 ua = *(const short8*)
                &Vb[((size_t)(bz * Cc + ct * 16 + l15)) * Np + m0 + quad * 8];
            #pragma unroll
            for (int t = 0; t < 2; t++)
                acc[ct][t] = __builtin_amdgcn_mfma_f32_16x16x32_bf16(
                    ua, pb[t], acc[ct][t], 0, 0, 0);
        }
    }
    unsigned short* po = PO + ((size_t)((bz * SL + by) * Cc)) * Np + nb;
    #pragma unroll
    for (int ct = 0; ct < 4; ct++)
        #pragma unroll
        for (int t = 0; t < 2; t++) {
            int c = ct * 16 + quad * 4, n = w * 32 + t * 16 + l15;
            #pragma unroll
            for (int r = 0; r < 4; r++)
                po[(size_t)(c + r) * Np + n] = (unsigned short)f2bf(acc[ct][t][r]);
        }
}

// ---------------- kernel 5: combine slices + gamma*out + x (8-wide) ----------------
__global__ __launch_bounds__(256) void combine_kernel(
    const unsigned short* __restrict__ PO, const float* __restrict__ x,
    const float* __restrict__ gamma, float* __restrict__ out, int sl2)
{
    int idx8 = (blockIdx.x * 256 + threadIdx.x) * 8;  // over Bn*Cc*Np
    int b = idx8 >> 18;
    int c = (idx8 >> 12) & 63;
    int n = idx8 & (Np - 1);
    float o[8];
    #pragma unroll
    for (int i = 0; i < 8; i++) o[i] = 0.f;
    for (int sl = 0; sl < sl2; ++sl) {
        uint4 u = *(const uint4*)&PO[(size_t)((b * sl2 + sl) * Cc + c) * Np + n];
        o[0] += bf2f(u.x & 0xffff); o[1] += bf2f(u.x >> 16);
        o[2] += bf2f(u.y & 0xffff); o[3] += bf2f(u.y >> 16);
        o[4] += bf2f(u.z & 0xffff); o[5] += bf2f(u.z >> 16);
        o[6] += bf2f(u.w & 0xffff); o[7] += bf2f(u.w >> 16);
    }
    float g = gamma[0];
    float4 x0 = *(const float4*)&x[idx8];
    float4 x1 = *(const float4*)&x[idx8 + 4];
    float4 r0 = make_float4(g * o[0] + x0.x, g * o[1] + x0.y,
                            g * o[2] + x0.z, g * o[3] + x0.w);
    float4 r1 = make_float4(g * o[4] + x1.x, g * o[5] + x1.y,
                            g * o[6] + x1.z, g * o[7] + x1.w);
    *(float4*)&out[idx8] = r0;
    *(float4*)&out[idx8 + 4] = r1;
}

extern "C" void kernel_launch(void* const* d_in, const int* in_sizes, int n_in,
                              void* d_out, int out_size, void* d_ws, size_t ws_size,
                              hipStream_t stream)
{
    const float* x     = (const float*)d_in[0];
    const float* Wq    = (const float*)d_in[1];
    const float* bq    = (const float*)d_in[2];
    const float* Wk    = (const float*)d_in[3];
    const float* bk    = (const float*)d_in[4];
    const float* Wv    = (const float*)d_in[5];
    const float* bv    = (const float*)d_in[6];
    const float* gamma = (const float*)d_in[7];
    float* out = (float*)d_out;

    unsigned short* Qp = (unsigned short*)d_ws;               // 1 MB
    unsigned short* Kp = Qp + (size_t)Bn * Np * QK_STR;       // 1 MB
    unsigned short* Vb = Kp + (size_t)Bn * Np * QK_STR;       // 2 MB (bf16 V, unnormalized)
    float* Zinv = (float*)(Vb + (size_t)Bn * Cc * Np);        // 64 KB
    float* ZP   = Zinv + (size_t)Bn * Np;                     // NSL partials, 256 KB
    unsigned short* PO = (unsigned short*)(ZP + (size_t)Bn * NSL * Np);  // SL * 2 MB

    size_t baseB = (size_t)Bn * Np * QK_STR * 2 * 2 + (size_t)Bn * Cc * Np * 2
                 + (size_t)Bn * Np * 4 + (size_t)Bn * NSL * Np * 4;
    int SL = 4;  // m-slices for attn partials
    while (SL > 1 && baseB + (size_t)Bn * SL * Cc * Np * 2 > ws_size) SL >>= 1;

    qkv_v2<<<dim3(Bn * Np / 64, 4), 64, 0, stream>>>(x, Wq, bq, Wk, bk, Wv, bv,
                                                     Qp, Kp, Vb);
    zsum_v2<<<dim3(Np / 64, NSL, Bn), 256, 0, stream>>>(Qp, Kp, ZP);
    zred<<<Bn * Np / 256, 256, 0, stream>>>(ZP, Zinv);
    attn_mfma<<<dim3(Np / 128, SL, Bn), 256, 0, stream>>>(Qp, Kp, Vb, Zinv,
                                                          PO, Np / SL, SL);
    combine_kernel<<<Bn * Cc * Np / (256 * 8), 256, 0, stream>>>(PO, x, gamma, out, SL);
}